// Round 1
// 720.078 us; speedup vs baseline: 1.4221x; 1.4221x over previous
//
#include <hip/hip_runtime.h>

#define N_TOK 131072
#define DIM   256
#define KCB   1024

#define RT    128          // rows per block
#define KT    128          // codes per kt chunk
#define TAU   1.0e-3f      // candidate margin; >=5x worst-case |dd' - dd_fp32|
#define EMIT_CAP 2048

typedef __attribute__((ext_vector_type(8))) short bf16x8;
typedef __attribute__((ext_vector_type(4))) float f32x4;

// RTNE fp32 -> bf16 (finite inputs only)
__device__ __forceinline__ unsigned short bf16_rtne(float v) {
  unsigned u = __float_as_uint(v);
  return (unsigned short)((u + 0x7FFFu + ((u >> 16) & 1u)) >> 16);
}
__device__ __forceinline__ float bf16_tof(unsigned short s) {
  return __uint_as_float(((unsigned)s) << 16);
}

// async global->LDS, 16B per lane; LDS dest must be wave-uniform base
__device__ __forceinline__ void gload_lds16(const short* g, short* l) {
  __builtin_amdgcn_global_load_lds(
      (const __attribute__((address_space(1))) void*)g,
      (__attribute__((address_space(3))) void*)l, 16, 0, 0);
}

// Bit-exact replica of numpy pairwise_sum over 128 floats of x*x.
__device__ __forceinline__ float np_sumsq_128(const float* __restrict__ p) {
#pragma clang fp contract(off)
  float4 a = *(const float4*)(p);
  float4 b = *(const float4*)(p + 4);
  float r0 = a.x * a.x, r1 = a.y * a.y, r2 = a.z * a.z, r3 = a.w * a.w;
  float r4 = b.x * b.x, r5 = b.y * b.y, r6 = b.z * b.z, r7 = b.w * b.w;
  for (int i = 8; i < 128; i += 8) {
    float4 c = *(const float4*)(p + i);
    float4 d = *(const float4*)(p + i + 4);
    r0 += c.x * c.x; r1 += c.y * c.y; r2 += c.z * c.z; r3 += c.w * c.w;
    r4 += d.x * d.x; r5 += d.y * d.y; r6 += d.z * d.z; r7 += d.w * d.w;
  }
  return ((r0 + r1) + (r2 + r3)) + ((r4 + r5) + (r6 + r7));
}

// K0a: ||c_k||^2 (same bits as before) + zero the fp64 loss accumulator.
__global__ void prep_cc(const float* __restrict__ cb, float* __restrict__ cc,
                        double* __restrict__ loss_acc) {
  int k = blockIdx.x * blockDim.x + threadIdx.x;
  if (k == 0) *loss_acc = 0.0;
  if (k < KCB) {
    const float* p = cb + (long)k * DIM;
    cc[k] = np_sumsq_128(p) + np_sumsq_128(p + 128);
  }
}

// K0b: split codebook into bf16 hi/lo planes, in MFMA-fragment-major tile
// layout: offset = kgrp*4096 + ds*512 + qd*128 + k15*8 + dl  (shorts)
//   k = kgrp*16 + k15, d = ds*32 + qd*8 + dl
// This makes argmin staging a pure linear global_load_lds copy and every
// b-fragment ds_read a linear (conflict-free) 1KB wave read.
__global__ void prep_split(const float* __restrict__ cb, short* __restrict__ ch,
                           short* __restrict__ cm) {
  int o = blockIdx.x * blockDim.x + threadIdx.x;  // output short index
  if (o < KCB * DIM) {
    int dl = o & 7, k15 = (o >> 3) & 15, qd = (o >> 7) & 3;
    int ds = (o >> 9) & 7, kg = o >> 12;
    int k = kg * 16 + k15, d = ds * 32 + qd * 8 + dl;
    float v = cb[k * DIM + d];
    unsigned short h = bf16_rtne(v);
    ch[o] = (short)h;
    cm[o] = (short)bf16_rtne(v - bf16_tof(h));
  }
}

// K1: MFMA 3-term distance + candidate emission + exact fmaf-chain recheck.
// z fragments held in registers (split once); codebook double-buffered via
// global_load_lds with a 2-phase prefetch pipeline.
__global__ __launch_bounds__(256, 2)
void argmin_kernel(const float* __restrict__ z, const float* __restrict__ cb,
                   const short* __restrict__ ch_g, const short* __restrict__ cm_g,
                   const float* __restrict__ cc_g, float* __restrict__ ids_f) {
  // [buf][plane h/m][8 kgrps * 512 shorts]
  __shared__ __align__(16) short cbuf[2][2][4096];
  __shared__ float zz_s[RT];
  __shared__ float zz_half[RT][2];
  __shared__ unsigned rowmin_s[RT];   // packed fp32 bits (positive -> monotonic)
  __shared__ int kmin_s[RT];
  __shared__ unsigned emit_s[EMIT_CAP];
  __shared__ int emit_cnt;

  const int t    = threadIdx.x;
  const int lane = t & 63;
  const int w    = t >> 6;       // wave 0..3, owns rows 32w..32w+31
  const int l15  = lane & 15;
  const int qd   = lane >> 4;    // quad 0..3
  const long rowbase = (long)blockIdx.x * RT;

  // ---- prologue: stage slice 0 (kt=0, ds=0) into cbuf[0] ----
#pragma unroll
  for (int i = 0; i < 2; ++i) {
    int g = 2 * w + i;   // kgrp within the kt chunk; wave-uniform
    gload_lds16(ch_g + g * 4096 + lane * 8, (short*)&cbuf[0][0][0] + g * 512);
    gload_lds16(cm_g + g * 4096 + lane * 8, (short*)&cbuf[0][1][0] + g * 512);
  }

  // ||z_row||^2, numpy order (bit-exact)
  {
    int r = t >> 1, h = t & 1;
    zz_half[r][h] = np_sumsq_128(z + (rowbase + r) * DIM + h * 128);
  }
  if (t < RT) { rowmin_s[t] = 0xFFFFFFFFu; kmin_s[t] = 0x7FFFFFFF; }
  if (t == 0) emit_cnt = 0;

  // ---- z A-fragments: load + hi/lo split ONCE per block, kept in VGPRs ----
  // lane holds z[row = 32w+16m+l15][ds*32 + qd*8 .. +7]  (same values as the
  // old per-slice LDS staging -> identical MFMA inputs -> identical dd' bits)
  bf16x8 a_h[2][8], a_m[2][8];
  {
    const float* zp0 = z + (rowbase + 32 * w + l15) * (long)DIM + qd * 8;
#pragma unroll
    for (int m = 0; m < 2; ++m) {
      const float* zp = zp0 + m * 16 * DIM;
#pragma unroll
      for (int ds = 0; ds < 8; ++ds) {
        float4 v0 = *(const float4*)(zp + ds * 32);
        float4 v1 = *(const float4*)(zp + ds * 32 + 4);
        float f[8] = {v0.x, v0.y, v0.z, v0.w, v1.x, v1.y, v1.z, v1.w};
#pragma unroll
        for (int j = 0; j < 8; ++j) {
          unsigned short hh = bf16_rtne(f[j]);
          a_h[m][ds][j] = (short)hh;
          a_m[m][ds][j] = (short)bf16_rtne(f[j] - bf16_tof(hh));
        }
      }
    }
  }

  __syncthreads();   // slice 0 staged (barrier drains vmcnt), zz_half visible
  if (t < RT) zz_s[t] = zz_half[t][0] + zz_half[t][1];
  // zz_s visibility for epilogue: guaranteed by the per-slice barriers below

#pragma clang loop unroll(disable)
  for (int kt = 0; kt < 8; ++kt) {
    f32x4 acc[2][8];
#pragma unroll
    for (int m = 0; m < 2; ++m)
#pragma unroll
      for (int c = 0; c < 8; ++c) acc[m][c] = (f32x4){0.f, 0.f, 0.f, 0.f};

    // ds fully unrolled so a_h[m][ds]/a_m[m][ds] are static register indices
#pragma unroll
    for (int ds = 0; ds < 8; ++ds) {
      // 2-phase pipeline: issue next slice's stage BEFORE this slice's MFMAs
      if (ds < 7 || kt < 7) {
        int ns = kt * 8 + ds + 1;
        long base = (long)(ns >> 3) * 32768 + (long)(ns & 7) * 512;
        short* dsth = (short*)&cbuf[(ds + 1) & 1][0][0];
        short* dstm = (short*)&cbuf[(ds + 1) & 1][1][0];
#pragma unroll
        for (int i = 0; i < 2; ++i) {
          int g = 2 * w + i;
          gload_lds16(ch_g + base + g * 4096 + lane * 8, dsth + g * 512);
          gload_lds16(cm_g + base + g * 4096 + lane * 8, dstm + g * 512);
        }
      }
      // compute on cbuf[ds&1]: b-frag reads are linear 1KB wave reads
      const short* bh = (const short*)&cbuf[ds & 1][0][0];
      const short* bm = (const short*)&cbuf[ds & 1][1][0];
#pragma unroll
      for (int c = 0; c < 8; ++c) {
        bf16x8 b_h = *(const bf16x8*)(bh + c * 512 + lane * 8);
        bf16x8 b_m = *(const bf16x8*)(bm + c * 512 + lane * 8);
#pragma unroll
        for (int m = 0; m < 2; ++m) {
          acc[m][c] = __builtin_amdgcn_mfma_f32_16x16x32_bf16(a_h[m][ds], b_h, acc[m][c], 0, 0, 0);
          acc[m][c] = __builtin_amdgcn_mfma_f32_16x16x32_bf16(a_h[m][ds], b_m, acc[m][c], 0, 0, 0);
          acc[m][c] = __builtin_amdgcn_mfma_f32_16x16x32_bf16(a_m[m][ds], b_h, acc[m][c], 0, 0, 0);
        }
      }
      if (ds < 7) __syncthreads();   // vmcnt(0)+barrier: next slice ready
    }

    // ---- kt epilogue: update per-row running min of dd' ----
    // C/D layout: col = lane&15 (code), row = quad*4 + reg (within 16-tile)
    float ccv[8];
#pragma unroll
    for (int c = 0; c < 8; ++c) ccv[c] = cc_g[kt * KT + 16 * c + l15];
    float rmin[2][4];
#pragma unroll
    for (int m = 0; m < 2; ++m)
#pragma unroll
      for (int rg = 0; rg < 4; ++rg) {
        int row = 32 * w + 16 * m + 4 * qd + rg;
        float zz = zz_s[row];
        float mn = __builtin_inff();
#pragma unroll
        for (int c = 0; c < 8; ++c) {
          float dv = (zz - 2.0f * acc[m][c][rg]) + ccv[c];
          mn = fminf(mn, dv);
        }
        rmin[m][rg] = mn;
      }
#pragma unroll
    for (int off = 1; off < 16; off <<= 1)
#pragma unroll
      for (int m = 0; m < 2; ++m)
#pragma unroll
        for (int rg = 0; rg < 4; ++rg)
          rmin[m][rg] = fminf(rmin[m][rg], __shfl_xor(rmin[m][rg], off, 64));
    if (l15 == 0) {
#pragma unroll
      for (int m = 0; m < 2; ++m)
#pragma unroll
        for (int rg = 0; rg < 4; ++rg)
          atomicMin(&rowmin_s[32 * w + 16 * m + 4 * qd + rg], __float_as_uint(rmin[m][rg]));
    }
    __syncthreads();   // rowmin complete; also drains next-kt slice-0 stage
    // ---- emission: dd' <= running_min + TAU (superset of exact-argmin+ties) ----
#pragma unroll
    for (int m = 0; m < 2; ++m)
#pragma unroll
      for (int rg = 0; rg < 4; ++rg) {
        int row = 32 * w + 16 * m + 4 * qd + rg;
        float th = __uint_as_float(rowmin_s[row]) + TAU;
        float zz = zz_s[row];
#pragma unroll
        for (int c = 0; c < 8; ++c) {
          int k = kt * KT + 16 * c + l15;
          float dv = (zz - 2.0f * acc[m][c][rg]) + ccv[c];
          if (dv <= th) {
            int idx = atomicAdd(&emit_cnt, 1);
            if (idx < EMIT_CAP) emit_s[idx] = ((unsigned)row << 10) | (unsigned)k;
          }
        }
      }
    // next kt's in-loop barriers separate emission from further rowmin updates
  }

  // ---- exact recheck of candidates: reproduces exact fp32 bits ----
  __syncthreads();
  int cnt = emit_cnt;
  bool over = cnt > EMIT_CAP;
  if (t < RT) rowmin_s[t] = 0xFFFFFFFFu;
  __syncthreads();

  if (!over) {
    unsigned mydd[8]; int myn[8], myk[8]; int mc = 0;
    for (int p = t; p < cnt; p += 256) {
      unsigned e = emit_s[p];
      int n = (int)(e >> 10), k = (int)(e & 1023);
      const float* zp = z + (rowbase + n) * DIM;
      const float* cp = cb + (long)k * DIM;
      float dot = 0.f;
      for (int d = 0; d < DIM; d += 4) {   // sequential fmaf chain, d ascending
        float4 zv = *(const float4*)(zp + d);
        float4 cv = *(const float4*)(cp + d);
        dot = fmaf(zv.x, cv.x, dot); dot = fmaf(zv.y, cv.y, dot);
        dot = fmaf(zv.z, cv.z, dot); dot = fmaf(zv.w, cv.w, dot);
      }
      float dd = (zz_s[n] - 2.0f * dot) + cc_g[k];
      mydd[mc] = __float_as_uint(dd); myn[mc] = n; myk[mc] = k; ++mc;
      atomicMin(&rowmin_s[n], __float_as_uint(dd));
    }
    __syncthreads();
    for (int i = 0; i < mc; ++i)
      if (mydd[i] == rowmin_s[myn[i]]) atomicMin(&kmin_s[myn[i]], myk[i]);
  } else {
    // pathological overflow fallback (never expected): exact full scan
    for (int p = t; p < RT * KCB; p += 256) {
      int n = p >> 10, k = p & 1023;
      const float* zp = z + (rowbase + n) * DIM;
      const float* cp = cb + (long)k * DIM;
      float dot = 0.f;
      for (int d = 0; d < DIM; d += 4) {
        float4 zv = *(const float4*)(zp + d);
        float4 cv = *(const float4*)(cp + d);
        dot = fmaf(zv.x, cv.x, dot); dot = fmaf(zv.y, cv.y, dot);
        dot = fmaf(zv.z, cv.z, dot); dot = fmaf(zv.w, cv.w, dot);
      }
      float dd = (zz_s[n] - 2.0f * dot) + cc_g[k];
      atomicMin(&rowmin_s[n], __float_as_uint(dd));
    }
    __syncthreads();
    for (int p = t; p < RT * KCB; p += 256) {
      int n = p >> 10, k = p & 1023;
      const float* zp = z + (rowbase + n) * DIM;
      const float* cp = cb + (long)k * DIM;
      float dot = 0.f;
      for (int d = 0; d < DIM; d += 4) {
        float4 zv = *(const float4*)(zp + d);
        float4 cv = *(const float4*)(cp + d);
        dot = fmaf(zv.x, cv.x, dot); dot = fmaf(zv.y, cv.y, dot);
        dot = fmaf(zv.z, cv.z, dot); dot = fmaf(zv.w, cv.w, dot);
      }
      float dd = (zz_s[n] - 2.0f * dot) + cc_g[k];
      if (__float_as_uint(dd) == rowmin_s[n]) atomicMin(&kmin_s[n], k);
    }
  }
  __syncthreads();
  if (t < RT) ids_f[rowbase + t] = (float)kmin_s[t];
}

// K2: out0 = z, out1 = codebook[ids], fp64 partial sum of (zq - z)^2
__global__ void output_kernel(const float* __restrict__ z, const float* __restrict__ cb,
                              const float* __restrict__ ids_f,
                              float* __restrict__ out_z, float* __restrict__ out_zq,
                              double* __restrict__ loss_acc) {
  __shared__ double red[4];
  double acc = 0.0;
  const long total4 = (long)N_TOK * DIM / 4;
  long idx    = (long)blockIdx.x * blockDim.x + threadIdx.x;
  long stride = (long)gridDim.x * blockDim.x;
  for (long i = idx; i < total4; i += stride) {
    long e = i * 4;
    long r = e >> 8;
    int  k = (int)ids_f[r];
    float4 vz = *(const float4*)(z + e);
    float4 vc = *(const float4*)(cb + (long)k * DIM + (e & 255));
    *(float4*)(out_z + e)  = vz;
    *(float4*)(out_zq + e) = vc;
    float d0 = vc.x - vz.x, d1 = vc.y - vz.y, d2 = vc.z - vz.z, d3 = vc.w - vz.w;
    acc += (double)(d0 * d0) + (double)(d1 * d1) + (double)(d2 * d2) + (double)(d3 * d3);
  }
#pragma unroll
  for (int off = 32; off > 0; off >>= 1) acc += __shfl_down(acc, off, 64);
  int lane = threadIdx.x & 63, wv = threadIdx.x >> 6;
  if (lane == 0) red[wv] = acc;
  __syncthreads();
  if (threadIdx.x == 0) {
    double s = (red[0] + red[1]) + (red[2] + red[3]);
    atomicAdd(loss_acc, s);
  }
}

// K3: loss = 1.25 * mean((zq - z)^2)
__global__ void finalize_kernel(const double* __restrict__ loss_acc,
                                float* __restrict__ out_loss) {
  if (threadIdx.x == 0) {
    double mean = *loss_acc / (double)((long)N_TOK * DIM);
    out_loss[0] = (float)(1.25 * mean);
  }
}

extern "C" void kernel_launch(void* const* d_in, const int* in_sizes, int n_in,
                              void* d_out, int out_size, void* d_ws, size_t ws_size,
                              hipStream_t stream) {
  const float* z  = (const float*)d_in[0];
  const float* cb = (const float*)d_in[1];
  float* out      = (float*)d_out;
  float* out_z    = out;                              // [N, D]
  float* out_zq   = out + (long)N_TOK * DIM;          // [N, D]
  float* out_ids  = out_zq + (long)N_TOK * DIM;       // [N] as fp32
  float* out_loss = out_ids + N_TOK;                  // [1]

  double* loss_acc = (double*)d_ws;                   // 8 B in ws

  // scratch inside the out_z region (dead until output_kernel overwrites it):
  // ch (512 KB) | cm (512 KB) | cc (4 KB)  -- all consumed before K2 writes out_z
  short* ch_g = (short*)((char*)d_out);
  short* cm_g = (short*)((char*)d_out + 524288);
  float* cc_g = (float*)((char*)d_out + 1048576);

  prep_cc<<<4, 256, 0, stream>>>(cb, cc_g, loss_acc);
  prep_split<<<KCB * DIM / 256, 256, 0, stream>>>(cb, ch_g, cm_g);
  argmin_kernel<<<N_TOK / RT, 256, 0, stream>>>(z, cb, ch_g, cm_g, cc_g, out_ids);
  output_kernel<<<2048, 256, 0, stream>>>(z, cb, out_ids, out_z, out_zq, loss_acc);
  finalize_kernel<<<1, 64, 0, stream>>>(loss_acc, out_loss);
}